// Round 8
// baseline (345.075 us; speedup 1.0000x reference)
//
#include <hip/hip_runtime.h>
#include <hip/hip_bf16.h>
#include <stdint.h>

#define NN   100000
#define NE   1600000
#define KIN  256
#define FOUT 128

typedef __attribute__((ext_vector_type(8))) short short8;
typedef __attribute__((ext_vector_type(4))) float f32x4;
typedef __attribute__((ext_vector_type(2))) float f32x2;

static __device__ __forceinline__ unsigned short f2bf(float f) {
  unsigned int u = __float_as_uint(f);
  u += 0x7fffu + ((u >> 16) & 1u);   // RNE (inputs finite)
  return (unsigned short)(u >> 16);
}

static __device__ __forceinline__ short8 pack8(float4 u, float4 v) {
  short8 r;
  r[0] = (short)f2bf(u.x); r[1] = (short)f2bf(u.y);
  r[2] = (short)f2bf(u.z); r[3] = (short)f2bf(u.w);
  r[4] = (short)f2bf(v.x); r[5] = (short)f2bf(v.y);
  r[6] = (short)f2bf(v.z); r[7] = (short)f2bf(v.w);
  return r;
}

// ---------------------------------------------------------------------------
// 1) prep: fused build_rowptr (blocks 0..12499) + convert_w (blocks 12500..
//    12755). R7 bug: convert half launched 512 blocks and decomposed n over
//    0..255 (FOUT is 128!) -> raced/corrupted wt matrix 1 and overran into h.
//    Fix: exactly 256 blocks = 65536 threads = 2*128*256 elements;
//    which = idx>>15, n = (idx&0x7fff)>>8 in 0..127, k = idx&255.
__global__ __launch_bounds__(256) void prep(const int* __restrict__ rows0,
                                            const int* __restrict__ rows1,
                                            int* __restrict__ rp0,
                                            int* __restrict__ rp1,
                                            const float* __restrict__ W0,
                                            const float* __restrict__ W1,
                                            unsigned short* __restrict__ wt) {
  const int b = blockIdx.x;
  if (b < 12500) {                      // rowptr part: 6250 blocks x 2 mats
    const int sub = b >= 6250 ? b - 6250 : b;
    const int mat = b >= 6250;
    const int e = sub * 256 + threadIdx.x;          // 6250*256 == NE exactly
    const int* rows = mat ? rows1 : rows0;
    int* rp = mat ? rp1 : rp0;
    int r1 = rows[e];
    int r2 = (e + 1 < NE) ? rows[e + 1] : NN;
    if (e == 0)
      for (int r = 0; r <= r1; ++r) rp[r] = 0;
    for (int r = r1 + 1; r <= r2; ++r) rp[r] = e + 1;
  } else {                              // convert part: 256 blocks exactly
    const int idx = (b - 12500) * 256 + threadIdx.x;   // 0..65535
    const int which = idx >> 15;        // 0..1
    const int rem = idx & 0x7fff;       // 0..32767
    const int n = rem >> 8;             // 0..127
    const int k = rem & 255;            // 0..255
    const float* W = which ? W1 : W0;
    wt[(size_t)which * (FOUT * KIN) + n * KIN + k] = f2bf(W[k * FOUT + n]);
  }
}

// ---------------------------------------------------------------------------
// 2) Fused dual-matrix GEMM v4: h[t] = bf16( x @ W[t] ), t = 0,1.
//    R6 analysis: v3's 4 in-loop __syncthreads each drain vmcnt(0), killing
//    the A-prefetch + DMA pipeline at 2 blocks/CU -> 61us vs ~25us HBM floor.
//    v4: wt is only 128KB -> stage ALL of B (2 mats, full K=256) into LDS
//    ONCE (single buffer, XOR-8 swizzle pre-applied to the GLOBAL source,
//    read side = proven R5 pattern), one barrier, then the entire K-loop
//    (8 steps x 16 MFMA) runs with ZERO barriers / zero global ops: all 16
//    A float4s issued right after the barrier, held in regs (64 VGPR).
//    8 waves x 16 rows = 128 rows/block, 1 block/CU (128KB LDS), VGPR ~180
//    <= 256 (launch_bounds(512,2) cap) so all 8 waves resident; HBM latency
//    hidden by co-resident waves' MFMAs, not re-exposed at barriers.
__global__ __launch_bounds__(512, 2) void gemm_fused(const float* __restrict__ x,
                                                     const unsigned short* __restrict__ wt,
                                                     unsigned short* __restrict__ h) {
  // [mat 2][col 128][slot 32] 16B slots (k=256); LINEAR dest for DMA,
  // swizzle in global source: LDS slot s holds global slot s^(col&7).
  __shared__ __align__(16) unsigned short bbuf[2 * 128 * 256];   // 128 KB

  const int tid  = threadIdx.x;      // 0..511
  const int lane = tid & 63;
  const int wv   = tid >> 6;         // 0..7
  const int m    = lane & 15;
  const int quad = lane >> 4;
  const int rowbase = blockIdx.x * 128 + wv * 16;

  int r  = rowbase + m;
  int rc = r < NN ? r : NN - 1;      // clamp loads; stores masked below
  const float* ap = x + (size_t)rc * KIN + quad * 8;

  // --- stage entire wt: 8192 pieces of 16B, 16 DMA ops per thread ---
  // piece pid = u*512+tid -> mat = pid>>12, col = (pid>>5)&127, s = pid&31
#pragma unroll
  for (int u = 0; u < 16; ++u) {
    int pid = u * 512 + tid;
    int tm = pid >> 12; int c = (pid >> 5) & 127; int s = pid & 31;
    const unsigned short* g = wt + (size_t)tm * (FOUT * KIN) + c * KIN +
                              ((s ^ (c & 7)) * 8);
    __builtin_amdgcn_global_load_lds(
        (const __attribute__((address_space(1))) void*)g,
        (__attribute__((address_space(3))) void*)
            &bbuf[(size_t)(u * 512 + wv * 64) * 8],
        16, 0, 0);
  }

  f32x4 acc[2][8];   // [mat][coltile]
#pragma unroll
  for (int t = 0; t < 2; ++t)
#pragma unroll
    for (int n = 0; n < 8; ++n)
      acc[t][n] = (f32x4){0.f, 0.f, 0.f, 0.f};

  __syncthreads();   // wt resident; drains only the DMA (A not yet issued)

  // --- issue ALL A loads now; hold in regs (16 float4 = 64 VGPR) ---
  float4 f[16];
#pragma unroll
  for (int s = 0; s < 8; ++s) {
    f[2 * s]     = *(const float4*)(ap + s * 32);
    f[2 * s + 1] = *(const float4*)(ap + s * 32 + 4);
  }

  // --- K-loop: zero barriers, zero global ops ---
#pragma unroll
  for (int s = 0; s < 8; ++s) {
    short8 a = pack8(f[2 * s], f[2 * s + 1]);
#pragma unroll
    for (int t = 0; t < 2; ++t)
#pragma unroll
      for (int n = 0; n < 8; ++n) {
        const int col = n * 16 + m;
        short8 b = *(const short8*)(&bbuf[0] + t * 32768 + col * 256 +
                                    (((s * 4 + quad) ^ (m & 7)) * 8));
        acc[t][n] = __builtin_amdgcn_mfma_f32_16x16x32_bf16(a, b, acc[t][n], 0, 0, 0);
      }
  }

  __syncthreads();   // all waves done reading wt -> LDS reusable

  // Epilogue: wave-private staging (8 waves x 4KB = 32KB) -> coalesced 16B.
  unsigned short* tile = &bbuf[0] + wv * 2048;    // 16 rows x 128 cols
#pragma unroll
  for (int t = 0; t < 2; ++t) {
    // D layout: col = lane&15 (=m), row = quad*4 + reg  [m89/m91 verified]
#pragma unroll
    for (int n = 0; n < 8; ++n)
#pragma unroll
      for (int reg = 0; reg < 4; ++reg)
        tile[(quad * 4 + reg) * 128 + n * 16 + m] = f2bf(acc[t][n][reg]);

    unsigned short* hh = h + (size_t)t * NN * FOUT;
#pragma unroll
    for (int p = 0; p < 4; ++p) {
      int row = p * 4 + quad;                        // 0..15
      uint4 v = *(const uint4*)&tile[row * 128 + m * 8];
      int grow = rowbase + row;
      if (grow < NN)
        *(uint4*)&hh[(size_t)grow * FOUT + m * 8] = v;
    }
  }
}

// ---------------------------------------------------------------------------
// 3) Fused SpMM + relu (exact R3 version — best measured, 123-124.8us).
//    One wave per row; lane = 2 features (256B/edge coalesced gather).
//    Main loop issues 8 gathers for BOTH matrices (16 outstanding) before
//    consuming either; unroll-4 tails. Edge metadata scalarized. NT store.
static __device__ __forceinline__ void consume8(const float* __restrict__ vals, int i,
                                                const unsigned* g, float& sx, float& sy) {
#pragma unroll
  for (int u = 0; u < 8; ++u) {
    float v = vals[i + u];
    sx += v * __uint_as_float(g[u] << 16);
    sy += v * __uint_as_float(g[u] & 0xffff0000u);
  }
}

static __device__ __forceinline__ void tail_spmm(const int* __restrict__ cols,
                                                 const float* __restrict__ vals,
                                                 const unsigned short* __restrict__ hsrc,
                                                 int i, int e, int fo,
                                                 float& sx, float& sy) {
  for (; i + 4 <= e; i += 4) {
    int c0 = cols[i], c1 = cols[i + 1], c2 = cols[i + 2], c3 = cols[i + 3];
    unsigned g0 = *(const unsigned*)(hsrc + (size_t)c0 * FOUT + fo);
    unsigned g1 = *(const unsigned*)(hsrc + (size_t)c1 * FOUT + fo);
    unsigned g2 = *(const unsigned*)(hsrc + (size_t)c2 * FOUT + fo);
    unsigned g3 = *(const unsigned*)(hsrc + (size_t)c3 * FOUT + fo);
    float v0 = vals[i], v1 = vals[i + 1], v2 = vals[i + 2], v3 = vals[i + 3];
    sx += v0 * __uint_as_float(g0 << 16);
    sy += v0 * __uint_as_float(g0 & 0xffff0000u);
    sx += v1 * __uint_as_float(g1 << 16);
    sy += v1 * __uint_as_float(g1 & 0xffff0000u);
    sx += v2 * __uint_as_float(g2 << 16);
    sy += v2 * __uint_as_float(g2 & 0xffff0000u);
    sx += v3 * __uint_as_float(g3 << 16);
    sy += v3 * __uint_as_float(g3 & 0xffff0000u);
  }
  for (; i < e; ++i) {
    int c = cols[i];
    float v = vals[i];
    unsigned g = *(const unsigned*)(hsrc + (size_t)c * FOUT + fo);
    sx += v * __uint_as_float(g << 16);
    sy += v * __uint_as_float(g & 0xffff0000u);
  }
}

__global__ __launch_bounds__(256) void spmm_relu(
    const int* __restrict__ rp0, const int* __restrict__ cols0, const float* __restrict__ vals0,
    const int* __restrict__ rp1, const int* __restrict__ cols1, const float* __restrict__ vals1,
    const unsigned short* __restrict__ h, float* __restrict__ out) {
  const int lane = threadIdx.x & 63;
  int r = blockIdx.x * 4 + (threadIdx.x >> 6);   // 25000*4 == NN exactly
  r = __builtin_amdgcn_readfirstlane(r);
  const int fo = lane * 2;

  const unsigned short* h0 = h;
  const unsigned short* h1 = h + (size_t)NN * FOUT;

  int i0 = __builtin_amdgcn_readfirstlane(rp0[r]);
  int e0 = __builtin_amdgcn_readfirstlane(rp0[r + 1]);
  int i1 = __builtin_amdgcn_readfirstlane(rp1[r]);
  int e1 = __builtin_amdgcn_readfirstlane(rp1[r + 1]);

  float sx = 0.f, sy = 0.f;

  // Main: dual-matrix batches, 16 gathers in flight.
  while (i0 + 8 <= e0 && i1 + 8 <= e1) {
    unsigned g0[8], g1[8];
#pragma unroll
    for (int u = 0; u < 8; ++u) {
      int c = cols0[i0 + u];                     // uniform -> s_load
      g0[u] = *(const unsigned*)(h0 + (size_t)c * FOUT + fo);
    }
#pragma unroll
    for (int u = 0; u < 8; ++u) {
      int c = cols1[i1 + u];
      g1[u] = *(const unsigned*)(h1 + (size_t)c * FOUT + fo);
    }
    consume8(vals0, i0, g0, sx, sy);
    consume8(vals1, i1, g1, sx, sy);
    i0 += 8;
    i1 += 8;
  }
  tail_spmm(cols0, vals0, h0, i0, e0, fo, sx, sy);
  tail_spmm(cols1, vals1, h1, i1, e1, fo, sx, sy);

  f32x2 o;
  o.x = sx > 0.f ? sx : 0.f;
  o.y = sy > 0.f ? sy : 0.f;
  __builtin_nontemporal_store(o, (f32x2*)(out + (size_t)r * FOUT + fo));
}

// ---------------------------------------------------------------------------
extern "C" void kernel_launch(void* const* d_in, const int* in_sizes, int n_in,
                              void* d_out, int out_size, void* d_ws, size_t ws_size,
                              hipStream_t stream) {
  const float* x     = (const float*)d_in[0];
  const int*   rows0 = (const int*)d_in[1];
  const int*   cols0 = (const int*)d_in[2];
  const float* vals0 = (const float*)d_in[3];
  const int*   rows1 = (const int*)d_in[4];
  const int*   cols1 = (const int*)d_in[5];
  const float* vals1 = (const float*)d_in[6];
  const float* W0    = (const float*)d_in[7];
  const float* W1    = (const float*)d_in[8];
  float* out = (float*)d_out;

  // ws layout (16B aligned):
  //   wt  : 2*128*256 bf16 =    131,072 B @ 0
  //   h   : 2*NN*128 bf16  = 51,200,000 B @ 131,072
  //   rp0 : (NN+1) i32     @ 51,331,072
  //   rp1 : (NN+1) i32     @ 51,731,136
  char* ws = (char*)d_ws;
  unsigned short* wt = (unsigned short*)(ws);
  unsigned short* h  = (unsigned short*)(ws + 131072);
  int* rp0 = (int*)(ws + 51331072);
  int* rp1 = (int*)(ws + 51731136);

  prep<<<12756, 256, 0, stream>>>(rows0, rows1, rp0, rp1, W0, W1, wt);
  gemm_fused<<<dim3((NN + 127) / 128, 1), 512, 0, stream>>>(x, wt, h);
  spmm_relu<<<25000, 256, 0, stream>>>(rp0, cols0, vals0, rp1, cols1, vals1, h, out);
}

// Round 9
// 336.150 us; speedup vs baseline: 1.0266x; 1.0266x over previous
//
#include <hip/hip_runtime.h>
#include <hip/hip_bf16.h>
#include <stdint.h>

#define NN   100000
#define NE   1600000
#define KIN  256
#define FOUT 128

typedef __attribute__((ext_vector_type(8))) short short8;
typedef __attribute__((ext_vector_type(4))) float f32x4;
typedef __attribute__((ext_vector_type(2))) float f32x2;

static __device__ __forceinline__ unsigned short f2bf(float f) {
  unsigned int u = __float_as_uint(f);
  u += 0x7fffu + ((u >> 16) & 1u);   // RNE (inputs finite)
  return (unsigned short)(u >> 16);
}

static __device__ __forceinline__ short8 pack8(float4 u, float4 v) {
  short8 r;
  r[0] = (short)f2bf(u.x); r[1] = (short)f2bf(u.y);
  r[2] = (short)f2bf(u.z); r[3] = (short)f2bf(u.w);
  r[4] = (short)f2bf(v.x); r[5] = (short)f2bf(v.y);
  r[6] = (short)f2bf(v.z); r[7] = (short)f2bf(v.w);
  return r;
}

// ---------------------------------------------------------------------------
// 1) W[k][n] fp32 -> wt[which][n][k] bf16 (transposed: B-frag = 16B contig).
__global__ void convert_w(const float* __restrict__ W0, const float* __restrict__ W1,
                          unsigned short* __restrict__ wt) {
  int n = blockIdx.x;          // 0..127
  int k = threadIdx.x;         // 0..255
  int which = blockIdx.y;
  const float* W = which ? W1 : W0;
  wt[(size_t)which * (FOUT * KIN) + n * KIN + k] = f2bf(W[k * FOUT + n]);
}

// ---------------------------------------------------------------------------
// 2) rows sorted -> CSR row_ptr, linear edge scan (lower_bound semantics).
__global__ __launch_bounds__(256) void build_rowptr(const int* __restrict__ rows0,
                                                    const int* __restrict__ rows1,
                                                    int* __restrict__ rp0,
                                                    int* __restrict__ rp1) {
  const int e = blockIdx.x * 256 + threadIdx.x;       // 6250*256 == NE exactly
  const int* rows = blockIdx.y ? rows1 : rows0;
  int* rp = blockIdx.y ? rp1 : rp0;
  int r1 = rows[e];
  int r2 = (e + 1 < NE) ? rows[e + 1] : NN;
  if (e == 0)
    for (int r = 0; r <= r1; ++r) rp[r] = 0;
  for (int r = r1 + 1; r <= r2; ++r) rp[r] = e + 1;
}

// ---------------------------------------------------------------------------
// 3) Fused dual-matrix GEMM v3.2: h[t] = bf16( x @ W[t] ), t = 0,1.
//    = R5's v3 (best measured: 2 blocks/CU, K=64 double-buffered DMA staging,
//    XOR-8 swizzle in the global source, 512thr/8 waves x 16 rows) with ONE
//    change: A-prefetch depth 2 (q0/q1/q2 named rotation, fully unrolled ->
//    compile-time regs). R8 showed the v4 occupancy halving loses; v3's slack
//    is A-latency inside the chunk (1 iter in flight vs ~900cy HBM). The
//    first two A-loads issue BEFORE the initial DMA so the prologue barrier
//    drain completes them for free. VGPR ~115 <= 128 (2 blocks/CU kept).
__global__ __launch_bounds__(512, 4) void gemm_fused(const float* __restrict__ x,
                                                     const unsigned short* __restrict__ wt,
                                                     unsigned short* __restrict__ h) {
  // [buf][mat 2][col 128][slot 8] 16B slots; LINEAR dest for DMA,
  // swizzle in global source: LDS slot s holds global slot s^(col&7).
  __shared__ __align__(16) unsigned short bbuf[2][2 * 128 * 64];   // 64 KB

  const int tid  = threadIdx.x;      // 0..511
  const int lane = tid & 63;
  const int wv   = tid >> 6;         // 0..7
  const int m    = lane & 15;
  const int quad = lane >> 4;
  const int rowbase = blockIdx.x * 128 + wv * 16;

  int r  = rowbase + m;
  int rc = r < NN ? r : NN - 1;      // clamp loads; stores masked below
  const float* ap = x + (size_t)rc * KIN + quad * 8;

  f32x4 acc[2][8];   // [mat][coltile]
#pragma unroll
  for (int t = 0; t < 2; ++t)
#pragma unroll
    for (int n = 0; n < 8; ++n)
      acc[t][n] = (f32x4){0.f, 0.f, 0.f, 0.f};

#define STAGE_DMA(ko_, buf_) do {                                              \
    _Pragma("unroll")                                                          \
    for (int u = 0; u < 4; ++u) {                                              \
      int pid = u * 512 + tid;                                                 \
      int tm = pid >> 10; int c = (pid >> 3) & 127; int s = pid & 7;           \
      const unsigned short* g = wt + (size_t)tm * (FOUT * KIN) + c * KIN +     \
                                (ko_) + ((s ^ (c & 7)) * 8);                   \
      __builtin_amdgcn_global_load_lds(                                        \
          (const __attribute__((address_space(1))) void*)g,                    \
          (__attribute__((address_space(3))) void*)                            \
              &bbuf[buf_][(size_t)(u * 512 + wv * 64) * 8],                    \
          16, 0, 0);                                                           \
    } } while (0)

  // A-pipeline depth 2: q0 = A(ki), q1 = A(ki+1), q2 = A(ki+2).
  // Issue the first two BEFORE the DMA: the prologue barrier's vmcnt drain
  // completes them at zero extra cost.
  float4 q0a = *(const float4*)(ap);
  float4 q0b = *(const float4*)(ap + 4);
  float4 q1a = *(const float4*)(ap + 32);
  float4 q1b = *(const float4*)(ap + 36);

  STAGE_DMA(0, 0);
  __syncthreads();

#pragma unroll
  for (int ci = 0; ci < 4; ++ci) {
    if (ci < 3) STAGE_DMA((ci + 1) * 64, (ci + 1) & 1);
#pragma unroll
    for (int kk = 0; kk < 2; ++kk) {
      const int ki = ci * 2 + kk;
      float4 q2a, q2b;
      if (ki + 2 < 8) {
        q2a = *(const float4*)(ap + (ki + 2) * 32);
        q2b = *(const float4*)(ap + (ki + 2) * 32 + 4);
      }
      short8 a = pack8(q0a, q0b);
      const unsigned short* bb = &bbuf[ci & 1][0];
#pragma unroll
      for (int t = 0; t < 2; ++t)
#pragma unroll
        for (int n = 0; n < 8; ++n) {
          const int col = n * 16 + m;
          short8 b = *(const short8*)(bb + t * 8192 + col * 64 +
                                      (((kk * 4 + quad) ^ (m & 7)) * 8));
          acc[t][n] = __builtin_amdgcn_mfma_f32_16x16x32_bf16(a, b, acc[t][n], 0, 0, 0);
        }
      q0a = q1a; q0b = q1b;
      q1a = q2a; q1b = q2b;
    }
    if (ci < 3) __syncthreads();   // drains DMA vmcnt + all waves' buf reads
  }
#undef STAGE_DMA

  __syncthreads();   // all waves done with bbuf -> reusable for epilogue

  // Epilogue: wave-private staging (8 waves x 4KB = 32KB in bbuf[0]).
  unsigned short* tile = &bbuf[0][0] + wv * 2048;    // 16 rows x 128 cols
#pragma unroll
  for (int t = 0; t < 2; ++t) {
    // D layout: col = lane&15 (=m), row = quad*4 + reg  [m89/m91 verified]
#pragma unroll
    for (int n = 0; n < 8; ++n)
#pragma unroll
      for (int reg = 0; reg < 4; ++reg)
        tile[(quad * 4 + reg) * 128 + n * 16 + m] = f2bf(acc[t][n][reg]);

    unsigned short* hh = h + (size_t)t * NN * FOUT;
#pragma unroll
    for (int p = 0; p < 4; ++p) {
      int row = p * 4 + quad;                        // 0..15
      uint4 v = *(const uint4*)&tile[row * 128 + m * 8];
      int grow = rowbase + row;
      if (grow < NN)
        *(uint4*)&hh[(size_t)grow * FOUT + m * 8] = v;
    }
  }
}

// ---------------------------------------------------------------------------
// 4) Fused SpMM + relu (exact R3 version — best measured, 123-124.8us).
//    One wave per row; lane = 2 features (256B/edge coalesced gather).
//    Main loop issues 8 gathers for BOTH matrices (16 outstanding) before
//    consuming either; unroll-4 tails. Edge metadata scalarized. NT store.
static __device__ __forceinline__ void consume8(const float* __restrict__ vals, int i,
                                                const unsigned* g, float& sx, float& sy) {
#pragma unroll
  for (int u = 0; u < 8; ++u) {
    float v = vals[i + u];
    sx += v * __uint_as_float(g[u] << 16);
    sy += v * __uint_as_float(g[u] & 0xffff0000u);
  }
}

static __device__ __forceinline__ void tail_spmm(const int* __restrict__ cols,
                                                 const float* __restrict__ vals,
                                                 const unsigned short* __restrict__ hsrc,
                                                 int i, int e, int fo,
                                                 float& sx, float& sy) {
  for (; i + 4 <= e; i += 4) {
    int c0 = cols[i], c1 = cols[i + 1], c2 = cols[i + 2], c3 = cols[i + 3];
    unsigned g0 = *(const unsigned*)(hsrc + (size_t)c0 * FOUT + fo);
    unsigned g1 = *(const unsigned*)(hsrc + (size_t)c1 * FOUT + fo);
    unsigned g2 = *(const unsigned*)(hsrc + (size_t)c2 * FOUT + fo);
    unsigned g3 = *(const unsigned*)(hsrc + (size_t)c3 * FOUT + fo);
    float v0 = vals[i], v1 = vals[i + 1], v2 = vals[i + 2], v3 = vals[i + 3];
    sx += v0 * __uint_as_float(g0 << 16);
    sy += v0 * __uint_as_float(g0 & 0xffff0000u);
    sx += v1 * __uint_as_float(g1 << 16);
    sy += v1 * __uint_as_float(g1 & 0xffff0000u);
    sx += v2 * __uint_as_float(g2 << 16);
    sy += v2 * __uint_as_float(g2 & 0xffff0000u);
    sx += v3 * __uint_as_float(g3 << 16);
    sy += v3 * __uint_as_float(g3 & 0xffff0000u);
  }
  for (; i < e; ++i) {
    int c = cols[i];
    float v = vals[i];
    unsigned g = *(const unsigned*)(hsrc + (size_t)c * FOUT + fo);
    sx += v * __uint_as_float(g << 16);
    sy += v * __uint_as_float(g & 0xffff0000u);
  }
}

__global__ __launch_bounds__(256) void spmm_relu(
    const int* __restrict__ rp0, const int* __restrict__ cols0, const float* __restrict__ vals0,
    const int* __restrict__ rp1, const int* __restrict__ cols1, const float* __restrict__ vals1,
    const unsigned short* __restrict__ h, float* __restrict__ out) {
  const int lane = threadIdx.x & 63;
  int r = blockIdx.x * 4 + (threadIdx.x >> 6);   // 25000*4 == NN exactly
  r = __builtin_amdgcn_readfirstlane(r);
  const int fo = lane * 2;

  const unsigned short* h0 = h;
  const unsigned short* h1 = h + (size_t)NN * FOUT;

  int i0 = __builtin_amdgcn_readfirstlane(rp0[r]);
  int e0 = __builtin_amdgcn_readfirstlane(rp0[r + 1]);
  int i1 = __builtin_amdgcn_readfirstlane(rp1[r]);
  int e1 = __builtin_amdgcn_readfirstlane(rp1[r + 1]);

  float sx = 0.f, sy = 0.f;

  // Main: dual-matrix batches, 16 gathers in flight.
  while (i0 + 8 <= e0 && i1 + 8 <= e1) {
    unsigned g0[8], g1[8];
#pragma unroll
    for (int u = 0; u < 8; ++u) {
      int c = cols0[i0 + u];                     // uniform -> s_load
      g0[u] = *(const unsigned*)(h0 + (size_t)c * FOUT + fo);
    }
#pragma unroll
    for (int u = 0; u < 8; ++u) {
      int c = cols1[i1 + u];
      g1[u] = *(const unsigned*)(h1 + (size_t)c * FOUT + fo);
    }
    consume8(vals0, i0, g0, sx, sy);
    consume8(vals1, i1, g1, sx, sy);
    i0 += 8;
    i1 += 8;
  }
  tail_spmm(cols0, vals0, h0, i0, e0, fo, sx, sy);
  tail_spmm(cols1, vals1, h1, i1, e1, fo, sx, sy);

  f32x2 o;
  o.x = sx > 0.f ? sx : 0.f;
  o.y = sy > 0.f ? sy : 0.f;
  __builtin_nontemporal_store(o, (f32x2*)(out + (size_t)r * FOUT + fo));
}

// ---------------------------------------------------------------------------
extern "C" void kernel_launch(void* const* d_in, const int* in_sizes, int n_in,
                              void* d_out, int out_size, void* d_ws, size_t ws_size,
                              hipStream_t stream) {
  const float* x     = (const float*)d_in[0];
  const int*   rows0 = (const int*)d_in[1];
  const int*   cols0 = (const int*)d_in[2];
  const float* vals0 = (const float*)d_in[3];
  const int*   rows1 = (const int*)d_in[4];
  const int*   cols1 = (const int*)d_in[5];
  const float* vals1 = (const float*)d_in[6];
  const float* W0    = (const float*)d_in[7];
  const float* W1    = (const float*)d_in[8];
  float* out = (float*)d_out;

  // ws layout (16B aligned):
  //   wt  : 2*128*256 bf16 =    131,072 B @ 0
  //   h   : 2*NN*128 bf16  = 51,200,000 B @ 131,072
  //   rp0 : (NN+1) i32     @ 51,331,072
  //   rp1 : (NN+1) i32     @ 51,731,136
  char* ws = (char*)d_ws;
  unsigned short* wt = (unsigned short*)(ws);
  unsigned short* h  = (unsigned short*)(ws + 131072);
  int* rp0 = (int*)(ws + 51331072);
  int* rp1 = (int*)(ws + 51731136);

  build_rowptr<<<dim3(6250, 2), 256, 0, stream>>>(rows0, rows1, rp0, rp1);
  convert_w<<<dim3(128, 2), 256, 0, stream>>>(W0, W1, wt);
  gemm_fused<<<dim3((NN + 127) / 128, 1), 512, 0, stream>>>(x, wt, h);
  spmm_relu<<<25000, 256, 0, stream>>>(rp0, cols0, vals0, rp1, cols1, vals1, h, out);
}

// Round 10
// 332.444 us; speedup vs baseline: 1.0380x; 1.0111x over previous
//
#include <hip/hip_runtime.h>
#include <hip/hip_bf16.h>
#include <stdint.h>

#define NN   100000
#define NE   1600000
#define KIN  256
#define FOUT 128

typedef __attribute__((ext_vector_type(8))) short short8;
typedef __attribute__((ext_vector_type(4))) float f32x4;
typedef __attribute__((ext_vector_type(2))) float f32x2;

static __device__ __forceinline__ unsigned short f2bf(float f) {
  unsigned int u = __float_as_uint(f);
  u += 0x7fffu + ((u >> 16) & 1u);   // RNE (inputs finite)
  return (unsigned short)(u >> 16);
}

static __device__ __forceinline__ short8 pack8(float4 u, float4 v) {
  short8 r;
  r[0] = (short)f2bf(u.x); r[1] = (short)f2bf(u.y);
  r[2] = (short)f2bf(u.z); r[3] = (short)f2bf(u.w);
  r[4] = (short)f2bf(v.x); r[5] = (short)f2bf(v.y);
  r[6] = (short)f2bf(v.z); r[7] = (short)f2bf(v.w);
  return r;
}

// ---------------------------------------------------------------------------
// 1) prep: fused build_rowptr (blocks 0..12499) + convert_w (blocks 12500..
//    12755). R8-validated version (passed, absmax 0.125). Single variable
//    this round: launch count 4 -> 3; gemm/spmm byte-identical to best
//    measured (R5 / R3).
__global__ __launch_bounds__(256) void prep(const int* __restrict__ rows0,
                                            const int* __restrict__ rows1,
                                            int* __restrict__ rp0,
                                            int* __restrict__ rp1,
                                            const float* __restrict__ W0,
                                            const float* __restrict__ W1,
                                            unsigned short* __restrict__ wt) {
  const int b = blockIdx.x;
  if (b < 12500) {                      // rowptr part: 6250 blocks x 2 mats
    const int sub = b >= 6250 ? b - 6250 : b;
    const int mat = b >= 6250;
    const int e = sub * 256 + threadIdx.x;          // 6250*256 == NE exactly
    const int* rows = mat ? rows1 : rows0;
    int* rp = mat ? rp1 : rp0;
    int r1 = rows[e];
    int r2 = (e + 1 < NE) ? rows[e + 1] : NN;
    if (e == 0)
      for (int r = 0; r <= r1; ++r) rp[r] = 0;
    for (int r = r1 + 1; r <= r2; ++r) rp[r] = e + 1;
  } else {                              // convert part: 256 blocks exactly
    const int idx = (b - 12500) * 256 + threadIdx.x;   // 0..65535
    const int which = idx >> 15;        // 0..1
    const int rem = idx & 0x7fff;       // 0..32767
    const int n = rem >> 8;             // 0..127
    const int k = rem & 255;            // 0..255
    const float* W = which ? W1 : W0;
    wt[(size_t)which * (FOUT * KIN) + n * KIN + k] = f2bf(W[k * FOUT + n]);
  }
}

// ---------------------------------------------------------------------------
// 2) Fused dual-matrix GEMM v3 (R5-exact, best measured ~62us):
//    512-thr blocks, 8 waves x 16 rows, wave tile 16x128x2mats (acc 64 VGPR).
//    B staged via global_load_lds width=16 in K=64 double-buffered chunks,
//    linear LDS dest, XOR-8 swizzle pre-applied to the GLOBAL source;
//    conflict-free ds_read_b128. A fp32 read once device-wide, depth-1
//    software pipeline (R9 showed depth-2 regresses). 2 blocks/CU.
__global__ __launch_bounds__(512, 4) void gemm_fused(const float* __restrict__ x,
                                                     const unsigned short* __restrict__ wt,
                                                     unsigned short* __restrict__ h) {
  __shared__ __align__(16) unsigned short bbuf[2][2 * 128 * 64];   // 64 KB

  const int tid  = threadIdx.x;      // 0..511
  const int lane = tid & 63;
  const int wv   = tid >> 6;         // 0..7
  const int m    = lane & 15;
  const int quad = lane >> 4;
  const int rowbase = blockIdx.x * 128 + wv * 16;

  int r  = rowbase + m;
  int rc = r < NN ? r : NN - 1;      // clamp loads; stores masked below
  const float* ap = x + (size_t)rc * KIN + quad * 8;

  f32x4 acc[2][8];   // [mat][coltile]
#pragma unroll
  for (int t = 0; t < 2; ++t)
#pragma unroll
    for (int n = 0; n < 8; ++n)
      acc[t][n] = (f32x4){0.f, 0.f, 0.f, 0.f};

#define STAGE_DMA(ko_, buf_) do {                                              \
    _Pragma("unroll")                                                          \
    for (int u = 0; u < 4; ++u) {                                              \
      int pid = u * 512 + tid;                                                 \
      int tm = pid >> 10; int c = (pid >> 3) & 127; int s = pid & 7;           \
      const unsigned short* g = wt + (size_t)tm * (FOUT * KIN) + c * KIN +     \
                                (ko_) + ((s ^ (c & 7)) * 8);                   \
      __builtin_amdgcn_global_load_lds(                                        \
          (const __attribute__((address_space(1))) void*)g,                    \
          (__attribute__((address_space(3))) void*)                            \
              &bbuf[buf_][(size_t)(u * 512 + wv * 64) * 8],                    \
          16, 0, 0);                                                           \
    } } while (0)

  float4 fc0 = *(const float4*)(ap);
  float4 fc1 = *(const float4*)(ap + 4);

  STAGE_DMA(0, 0);
  __syncthreads();

#pragma unroll
  for (int ci = 0; ci < 4; ++ci) {
    if (ci < 3) STAGE_DMA((ci + 1) * 64, (ci + 1) & 1);
#pragma unroll
    for (int kk = 0; kk < 2; ++kk) {
      const int ki = ci * 2 + kk;
      float4 fn0, fn1;
      if (ki < 7) {
        fn0 = *(const float4*)(ap + (ki + 1) * 32);
        fn1 = *(const float4*)(ap + (ki + 1) * 32 + 4);
      }
      short8 a = pack8(fc0, fc1);
      const unsigned short* bb = &bbuf[ci & 1][0];
#pragma unroll
      for (int t = 0; t < 2; ++t)
#pragma unroll
        for (int n = 0; n < 8; ++n) {
          const int col = n * 16 + m;
          short8 b = *(const short8*)(bb + t * 8192 + col * 64 +
                                      (((kk * 4 + quad) ^ (m & 7)) * 8));
          acc[t][n] = __builtin_amdgcn_mfma_f32_16x16x32_bf16(a, b, acc[t][n], 0, 0, 0);
        }
      fc0 = fn0; fc1 = fn1;
    }
    if (ci < 3) __syncthreads();   // drains DMA vmcnt + all waves' buf reads
  }
#undef STAGE_DMA

  // Epilogue: wave-private staging in bbuf[0] (all waves past their last
  // bbuf[0] read after the ci=2-end barrier; ci=3 reads only bbuf[1];
  // regions below are wave-private). 8 waves x 4KB = 32KB.
  unsigned short* tile = &bbuf[0][0] + wv * 2048;    // 16 rows x 128 cols
#pragma unroll
  for (int t = 0; t < 2; ++t) {
    // D layout: col = lane&15 (=m), row = quad*4 + reg  [m89/m91 verified]
#pragma unroll
    for (int n = 0; n < 8; ++n)
#pragma unroll
      for (int reg = 0; reg < 4; ++reg)
        tile[(quad * 4 + reg) * 128 + n * 16 + m] = f2bf(acc[t][n][reg]);

    unsigned short* hh = h + (size_t)t * NN * FOUT;
#pragma unroll
    for (int p = 0; p < 4; ++p) {
      int row = p * 4 + quad;                        // 0..15
      uint4 v = *(const uint4*)&tile[row * 128 + m * 8];
      int grow = rowbase + row;
      if (grow < NN)
        *(uint4*)&hh[(size_t)grow * FOUT + m * 8] = v;
    }
  }
}

// ---------------------------------------------------------------------------
// 3) Fused SpMM + relu (exact R3 version — best measured, 123-125us x5).
//    One wave per row; lane = 2 features (256B/edge coalesced gather).
//    Main loop issues 8 gathers for BOTH matrices (16 outstanding) before
//    consuming either; unroll-4 tails. Edge metadata scalarized. NT store.
static __device__ __forceinline__ void consume8(const float* __restrict__ vals, int i,
                                                const unsigned* g, float& sx, float& sy) {
#pragma unroll
  for (int u = 0; u < 8; ++u) {
    float v = vals[i + u];
    sx += v * __uint_as_float(g[u] << 16);
    sy += v * __uint_as_float(g[u] & 0xffff0000u);
  }
}

static __device__ __forceinline__ void tail_spmm(const int* __restrict__ cols,
                                                 const float* __restrict__ vals,
                                                 const unsigned short* __restrict__ hsrc,
                                                 int i, int e, int fo,
                                                 float& sx, float& sy) {
  for (; i + 4 <= e; i += 4) {
    int c0 = cols[i], c1 = cols[i + 1], c2 = cols[i + 2], c3 = cols[i + 3];
    unsigned g0 = *(const unsigned*)(hsrc + (size_t)c0 * FOUT + fo);
    unsigned g1 = *(const unsigned*)(hsrc + (size_t)c1 * FOUT + fo);
    unsigned g2 = *(const unsigned*)(hsrc + (size_t)c2 * FOUT + fo);
    unsigned g3 = *(const unsigned*)(hsrc + (size_t)c3 * FOUT + fo);
    float v0 = vals[i], v1 = vals[i + 1], v2 = vals[i + 2], v3 = vals[i + 3];
    sx += v0 * __uint_as_float(g0 << 16);
    sy += v0 * __uint_as_float(g0 & 0xffff0000u);
    sx += v1 * __uint_as_float(g1 << 16);
    sy += v1 * __uint_as_float(g1 & 0xffff0000u);
    sx += v2 * __uint_as_float(g2 << 16);
    sy += v2 * __uint_as_float(g2 & 0xffff0000u);
    sx += v3 * __uint_as_float(g3 << 16);
    sy += v3 * __uint_as_float(g3 & 0xffff0000u);
  }
  for (; i < e; ++i) {
    int c = cols[i];
    float v = vals[i];
    unsigned g = *(const unsigned*)(hsrc + (size_t)c * FOUT + fo);
    sx += v * __uint_as_float(g << 16);
    sy += v * __uint_as_float(g & 0xffff0000u);
  }
}

__global__ __launch_bounds__(256) void spmm_relu(
    const int* __restrict__ rp0, const int* __restrict__ cols0, const float* __restrict__ vals0,
    const int* __restrict__ rp1, const int* __restrict__ cols1, const float* __restrict__ vals1,
    const unsigned short* __restrict__ h, float* __restrict__ out) {
  const int lane = threadIdx.x & 63;
  int r = blockIdx.x * 4 + (threadIdx.x >> 6);   // 25000*4 == NN exactly
  r = __builtin_amdgcn_readfirstlane(r);
  const int fo = lane * 2;

  const unsigned short* h0 = h;
  const unsigned short* h1 = h + (size_t)NN * FOUT;

  int i0 = __builtin_amdgcn_readfirstlane(rp0[r]);
  int e0 = __builtin_amdgcn_readfirstlane(rp0[r + 1]);
  int i1 = __builtin_amdgcn_readfirstlane(rp1[r]);
  int e1 = __builtin_amdgcn_readfirstlane(rp1[r + 1]);

  float sx = 0.f, sy = 0.f;

  // Main: dual-matrix batches, 16 gathers in flight.
  while (i0 + 8 <= e0 && i1 + 8 <= e1) {
    unsigned g0[8], g1[8];
#pragma unroll
    for (int u = 0; u < 8; ++u) {
      int c = cols0[i0 + u];                     // uniform -> s_load
      g0[u] = *(const unsigned*)(h0 + (size_t)c * FOUT + fo);
    }
#pragma unroll
    for (int u = 0; u < 8; ++u) {
      int c = cols1[i1 + u];
      g1[u] = *(const unsigned*)(h1 + (size_t)c * FOUT + fo);
    }
    consume8(vals0, i0, g0, sx, sy);
    consume8(vals1, i1, g1, sx, sy);
    i0 += 8;
    i1 += 8;
  }
  tail_spmm(cols0, vals0, h0, i0, e0, fo, sx, sy);
  tail_spmm(cols1, vals1, h1, i1, e1, fo, sx, sy);

  f32x2 o;
  o.x = sx > 0.f ? sx : 0.f;
  o.y = sy > 0.f ? sy : 0.f;
  __builtin_nontemporal_store(o, (f32x2*)(out + (size_t)r * FOUT + fo));
}

// ---------------------------------------------------------------------------
extern "C" void kernel_launch(void* const* d_in, const int* in_sizes, int n_in,
                              void* d_out, int out_size, void* d_ws, size_t ws_size,
                              hipStream_t stream) {
  const float* x     = (const float*)d_in[0];
  const int*   rows0 = (const int*)d_in[1];
  const int*   cols0 = (const int*)d_in[2];
  const float* vals0 = (const float*)d_in[3];
  const int*   rows1 = (const int*)d_in[4];
  const int*   cols1 = (const int*)d_in[5];
  const float* vals1 = (const float*)d_in[6];
  const float* W0    = (const float*)d_in[7];
  const float* W1    = (const float*)d_in[8];
  float* out = (float*)d_out;

  // ws layout (16B aligned):
  //   wt  : 2*128*256 bf16 =    131,072 B @ 0
  //   h   : 2*NN*128 bf16  = 51,200,000 B @ 131,072
  //   rp0 : (NN+1) i32     @ 51,331,072
  //   rp1 : (NN+1) i32     @ 51,731,136
  char* ws = (char*)d_ws;
  unsigned short* wt = (unsigned short*)(ws);
  unsigned short* h  = (unsigned short*)(ws + 131072);
  int* rp0 = (int*)(ws + 51331072);
  int* rp1 = (int*)(ws + 51731136);

  prep<<<12756, 256, 0, stream>>>(rows0, rows1, rp0, rp1, W0, W1, wt);
  gemm_fused<<<dim3((NN + 127) / 128, 1), 512, 0, stream>>>(x, wt, h);
  spmm_relu<<<25000, 256, 0, stream>>>(rp0, cols0, vals0, rp1, cols1, vals1, h, out);
}